// Round 16
// baseline (934.556 us; speedup 1.0000x reference)
//
#include <hip/hip_runtime.h>
#include <hip/hip_bf16.h>
#include <stdint.h>

// Problem constants (from setup_inputs)
#define N_TOK 8192
#define C_DIM 2048
#define E_NUM 8
#define H_DIM 1408
#define HS_DIM 2816
#define NRPAD 18432      // 16384 routed slots + per-expert padding to 256
#define MAXT256 72       // 64 full tiles + 8 partial
#define NBXA 704         // shared-up blocks (32 mt x 22 nt)
#define NBXB 792         // routed-up blocks (72 mt x 11 nt)
#define NBCVT 2048       // cvt sub-grid in prep kernel (sgw+upw)
#define NBCV2 512        // cvt tail blocks inside gemm_up2 (sdw+dww)

typedef unsigned short u16;
typedef float f32x4_t __attribute__((ext_vector_type(4)));
typedef short bf16x8_t __attribute__((ext_vector_type(8)));

__device__ __forceinline__ u16 f2bf(float f) {
  union { float f; uint32_t u; } c; c.f = f;
  uint32_t u = c.u;
  return (u16)((u + 0x7fffu + ((u >> 16) & 1u)) >> 16);
}
__device__ __forceinline__ float bf2f(u16 b) {
  union { uint32_t u; float f; } c; c.u = ((uint32_t)b) << 16;
  return c.f;
}

__device__ __forceinline__ void async_copy16(const u16* gsrc, u16* ldst) {
  __builtin_amdgcn_global_load_lds(
      (const __attribute__((address_space(1))) void*)gsrc,
      (__attribute__((address_space(3))) void*)ldst, 16, 0, 0);
}

#define BARRIER() asm volatile("s_barrier" ::: "memory")
#define WAITV4()  asm volatile("s_waitcnt vmcnt(4)" ::: "memory")
#define WAITV0()  asm volatile("s_waitcnt vmcnt(0)" ::: "memory")

// ---------------- prep: fused {sgw+upw cvt} + {gate/top-2/x_bf} ---------------
__global__ __launch_bounds__(256) void prep_kernel(
    const float* __restrict__ s0, u16* __restrict__ d0, int n0,
    const float* __restrict__ s1, u16* __restrict__ d1, int n1,
    const float* __restrict__ x, const float* __restrict__ gw,
    const float* __restrict__ gbias, u16* __restrict__ x_bf,
    int* __restrict__ tok_e, float* __restrict__ tok_w, int* __restrict__ counts) {
  if (blockIdx.x < NBCVT) {
    int total = n0 + n1;
    int i = blockIdx.x * blockDim.x + threadIdx.x;
    const int stride = NBCVT * 256;
    for (; i < total; i += stride) {
      const float* src; u16* dst; int j = i;
      if (j < n0) { src = s0; dst = d0; }
      else { j -= n0; src = s1; dst = d1; }
      float4 v = ((const float4*)src)[j];
      ushort4 u;
      u.x = f2bf(v.x); u.y = f2bf(v.y); u.z = f2bf(v.z); u.w = f2bf(v.w);
      ((ushort4*)dst)[j] = u;
    }
    return;
  }
  int n = blockIdx.x - NBCVT;
  const float* xr = x + (size_t)n * C_DIM;
  u16* xbr = x_bf + (size_t)n * C_DIM;
  int t = threadIdx.x;
  float acc[E_NUM];
#pragma unroll
  for (int e = 0; e < E_NUM; ++e) acc[e] = 0.f;
  for (int k0 = t * 4; k0 < C_DIM; k0 += 1024) {
    float4 xv = *(const float4*)(xr + k0);
    ushort4 xb;
    xb.x = f2bf(xv.x); xb.y = f2bf(xv.y); xb.z = f2bf(xv.z); xb.w = f2bf(xv.w);
    *(ushort4*)(xbr + k0) = xb;
#pragma unroll
    for (int e = 0; e < E_NUM; ++e) {
      float4 gv = *(const float4*)(gw + e * C_DIM + k0);
      acc[e] += xv.x * gv.x + xv.y * gv.y + xv.z * gv.z + xv.w * gv.w;
    }
  }
#pragma unroll
  for (int e = 0; e < E_NUM; ++e)
    for (int off = 32; off > 0; off >>= 1) acc[e] += __shfl_xor(acc[e], off, 64);
  __shared__ float sred[4][E_NUM];
  int wid = t >> 6, lane = t & 63;
  if (lane == 0) {
#pragma unroll
    for (int e = 0; e < E_NUM; ++e) sred[wid][e] = acc[e];
  }
  __syncthreads();
  if (t == 0) {
    float sc[E_NUM];
#pragma unroll
    for (int e = 0; e < E_NUM; ++e) {
      float s = sred[0][e] + sred[1][e] + sred[2][e] + sred[3][e];
      sc[e] = 1.f / (1.f + expf(-s));
    }
    int e0 = 0; float k0v = sc[0] + gbias[0];
    for (int e = 1; e < E_NUM; ++e) {
      float ke = sc[e] + gbias[e];
      if (ke > k0v) { k0v = ke; e0 = e; }
    }
    int e1 = -1; float k1v = -1e30f;
    for (int e = 0; e < E_NUM; ++e) {
      if (e == e0) continue;
      float ke = sc[e] + gbias[e];
      if (ke > k1v) { k1v = ke; e1 = e; }
    }
    float w0 = sc[e0], w1 = sc[e1];
    float s = w0 + w1;
    w0 /= s; w1 /= s;
    tok_e[2 * n] = e0; tok_e[2 * n + 1] = e1;
    tok_w[2 * n] = w0; tok_w[2 * n + 1] = w1;
    atomicAdd(&counts[e0], 1);
    atomicAdd(&counts[e1], 1);
  }
}

// -------- route: merged {256-padded scan + tile table} + slot build ----------
__global__ __launch_bounds__(256) void route_kernel(
    const int* __restrict__ counts, const int* __restrict__ tok_e,
    int* __restrict__ cursor, int* __restrict__ slot_tok, int* __restrict__ slot_of,
    int* __restrict__ tile_e, int* __restrict__ tile_s0, int* __restrict__ ntiles) {
  // redundant per-thread 8-expert scan (cheap, avoids a separate launch)
  int off_pad[E_NUM];
  {
    int off = 0;
#pragma unroll
    for (int e = 0; e < E_NUM; ++e) {
      off_pad[e] = off;
      off += ((counts[e] + 255) >> 8) << 8;
    }
  }
  if (blockIdx.x == 0 && threadIdx.x == 0) {
    int t = 0;
    for (int e = 0; e < E_NUM; ++e) {
      int tiles = (counts[e] + 255) >> 8;
      for (int i = 0; i < tiles; ++i) { tile_e[t] = e; tile_s0[t] = off_pad[e] + i * 256; ++t; }
    }
    *ntiles = t;
  }
  int n = blockIdx.x * blockDim.x + threadIdx.x;
  if (n >= N_TOK) return;
#pragma unroll
  for (int j = 0; j < 2; ++j) {
    int e = tok_e[2 * n + j];
    int pos = atomicAdd(&cursor[e], 1);
    int s = off_pad[e] + pos;
    slot_tok[s] = n;
    slot_of[2 * n + j] = s;
  }
}

// ======== shared GEMM-core macros (8-phase, single vmcnt(4)/K-tile) ==========
#define STG_A(BUF, KST, KS) \
  async_copy16(aS[0] + (KST) + (KS)*32, &lds[(BUF) + (KS)*8192 + wst]); \
  async_copy16(aS[1] + (KST) + (KS)*32, &lds[(BUF) + (KS)*8192 + 4096 + wst]);
#define STG_B(BUF, KST, KS) \
  async_copy16(bS[0] + (KST) + (KS)*32, &lds[(BUF) + 16384 + (KS)*8192 + wst]); \
  async_copy16(bS[1] + (KST) + (KS)*32, &lds[(BUF) + 16384 + (KS)*8192 + 4096 + wst]);
#define LDA(QM, KS) \
  _Pragma("unroll") \
  for (int m = 0; m < 4; ++m) { \
    int row = (wm << 7) + (QM)*64 + (m << 4) + fr; \
    afr[m] = *(const bf16x8_t*)&lds[cur + (KS)*8192 + (row << 5) + swz]; \
  }
#define LDB(KS) \
  _Pragma("unroll") \
  for (int n = 0; n < 4; ++n) { \
    int row = (wn << 6) + (n << 4) + fr; \
    bfr[n] = *(const bf16x8_t*)&lds[cur + 16384 + (KS)*8192 + (row << 5) + swz]; \
  }
#define MFMA16(QM) \
  __builtin_amdgcn_s_setprio(1); \
  _Pragma("unroll") \
  for (int m = 0; m < 4; ++m) \
    _Pragma("unroll") \
    for (int n = 0; n < 4; ++n) \
      acc[(QM)*4 + m][n] = __builtin_amdgcn_mfma_f32_16x16x32_bf16( \
          afr[m], bfr[n], acc[(QM)*4 + m][n], 0, 0, 0); \
  __builtin_amdgcn_s_setprio(0);

#define GEMM_PROLOGUE(KT) \
  STG_A(0, 0, 0); STG_B(0, 0, 0); STG_A(0, 0, 1); STG_B(0, 0, 1); \
  STG_A(32768, 64, 0); STG_B(32768, 64, 0); \
  WAITV4(); \
  BARRIER();

#define GEMM_KLOOP(KT) \
  for (int kt = 0; kt < (KT); ++kt) { \
    const int cur = (kt & 1) << 15; \
    const int nxtb = ((kt + 1) & 1) << 15; \
    const int kst1 = (kt + 1 < (KT) ? kt + 1 : kt) << 6; \
    const int kst2 = (kt + 2 < (KT) ? kt + 2 : (KT) - 1) << 6; \
    bf16x8_t afr[4], bfr[4]; \
    LDB(0); LDA(0, 0); STG_A(nxtb, kst1, 1); \
    BARRIER(); MFMA16(0); BARRIER(); \
    LDA(1, 0); STG_B(nxtb, kst1, 1); \
    BARRIER(); MFMA16(1); BARRIER(); \
    LDB(1); LDA(0, 1); STG_A(cur, kst2, 0); \
    BARRIER(); MFMA16(0); BARRIER(); \
    LDA(1, 1); STG_B(cur, kst2, 0); \
    BARRIER(); MFMA16(1); \
    WAITV4(); \
    BARRIER(); \
  } \
  WAITV0();

// ---------------- merged up-GEMM + deferred cvt tail in ONE launch ------------
// Blocks [0,NBXA): shared-up.  [NBXA,NBXA+NBXB): routed-up.
// [NBXA+NBXB, +NBCV2): bf16 conversion of sdw+dww (needed only by the later
// down-GEMM launches; these BW-bound blocks dispatch last and fill the tail
// idle of the final partial block-wave).
__global__ __launch_bounds__(512, 2) void gemm_up2(
    const u16* __restrict__ x_bf, const u16* __restrict__ sgw_bf,
    const u16* __restrict__ upw_bf, u16* __restrict__ h_sh, u16* __restrict__ h_rt,
    const int* __restrict__ tile_e, const int* __restrict__ tile_s0,
    const int* __restrict__ ntiles, const int* __restrict__ slot_tok,
    const float* __restrict__ sdw, u16* __restrict__ sdw_bf,
    const float* __restrict__ dww, u16* __restrict__ dww_bf) {
  const int bxr = blockIdx.x;
  if (bxr >= NBXA + NBXB) {
    // deferred weight conversion (sdw then dww), grid-stride over float4s
    const int n0 = C_DIM * HS_DIM / 4;
    const int n1 = E_NUM * C_DIM * H_DIM / 4;
    int total = n0 + n1;
    int i = (bxr - (NBXA + NBXB)) * 512 + (int)threadIdx.x;
    const int stride = NBCV2 * 512;
    for (; i < total; i += stride) {
      const float* src; u16* dst; int j = i;
      if (j < n0) { src = sdw; dst = sdw_bf; }
      else { j -= n0; src = dww; dst = dww_bf; }
      float4 v = ((const float4*)src)[j];
      ushort4 u;
      u.x = f2bf(v.x); u.y = f2bf(v.y); u.z = f2bf(v.z); u.w = f2bf(v.w);
      ((ushort4*)dst)[j] = u;
    }
    return;
  }
  const bool routed = (bxr >= NBXA);
  const int lidx = routed ? (bxr - NBXA) : bxr;
  const int nbx  = routed ? NBXB : NBXA;
  const int nbn  = routed ? 11 : 22;
  const int ldo  = routed ? H_DIM : HS_DIM;
  const int silb = routed ? 0 : HS_DIM;
  const int mulb = routed ? H_DIM : 0;
  u16* Outp      = routed ? h_rt : h_sh;

  const int chunk = nbx >> 3;
  const int l = (lidx & 7) * chunk + (lidx >> 3);
  const int bandsz = nbn << 2;
  const int band = l / bandsz;
  const int rem = l - band * bandsz;
  const int nt = rem >> 2;
  const int mt = (band << 2) + (rem & 3);
  int m0;
  const u16* Bb;
  if (routed) {
    if (mt >= *ntiles) return;
    m0 = tile_s0[mt];
    Bb = upw_bf + (size_t)tile_e[mt] * ((size_t)(2 * H_DIM) * C_DIM);
  } else {
    m0 = mt << 8;
    Bb = sgw_bf;
  }
  const int h0 = nt << 7;

  __shared__ u16 lds[65536];   // [buf(2)][mat(2)][ks(2)][256][32]

  const int t = threadIdx.x;
  const int w = t >> 6, lane = t & 63;
  const int wst = w << 9;
  const int rt2 = t >> 2;
  const int coff = (((t & 3) ^ ((rt2 >> 1) & 3)) << 3);
  const u16* aS[2]; const u16* bS[2];
#pragma unroll
  for (int j = 0; j < 2; ++j) {
    int r = (j << 7) + rt2;
    int arow = routed ? slot_tok[m0 + r] : (m0 + r);
    aS[j] = x_bf + (size_t)arow * C_DIM + coff;
    int grow = (((r >> 4) & 1) ? mulb : silb) + h0 + ((r >> 5) << 4) + (r & 15);
    bS[j] = Bb + (size_t)grow * C_DIM + coff;
  }

  const int wm = w >> 2, wn = w & 3;
  const int fr = lane & 15, kq = lane >> 4;
  const int swz = ((kq ^ ((fr >> 1) & 3)) << 3);

  f32x4_t acc[8][4];
  f32x4_t zero4 = {0.f, 0.f, 0.f, 0.f};
#pragma unroll
  for (int m = 0; m < 8; ++m)
#pragma unroll
    for (int n = 0; n < 4; ++n) acc[m][n] = zero4;

  const int KT = C_DIM >> 6;
  GEMM_PROLOGUE(KT)
  GEMM_KLOOP(KT)

  // fused SwiGLU epilogue
#pragma unroll
  for (int mf = 0; mf < 8; ++mf) {
    const int rb = (wm << 7) + (mf << 4) + (kq << 2);
#pragma unroll
    for (int rr = 0; rr < 4; ++rr) {
      const int row = m0 + rb + rr;
      u16* orow = Outp + (size_t)row * ldo;
#pragma unroll
      for (int jj = 0; jj < 2; ++jj) {
        float g = acc[mf][2 * jj][rr];
        float uu = acc[mf][2 * jj + 1][rr];
        float hv = (g / (1.f + __expf(-g))) * uu;
        orow[h0 + (wn << 5) + (jj << 4) + fr] = f2bf(hv);
      }
    }
  }
}

// ---------------- 256x256x64 8-phase bf16 GEMM (down-proj variants) ----------
template <bool ROUTE, bool COMBINE>
__global__ __launch_bounds__(512, 2) void gemm256(
    const u16* __restrict__ A, const u16* __restrict__ B,
    void* __restrict__ Out, int ldo, int K, int nbn,
    const int* __restrict__ tile_e, const int* __restrict__ tile_s0,
    const int* __restrict__ ntiles, long estride,
    const int* __restrict__ slot_of, const float* __restrict__ tok_w,
    const u16* __restrict__ p_rt) {
  const int chunk = gridDim.x >> 3;
  const int orig = blockIdx.x;
  const int l = (orig & 7) * chunk + (orig >> 3);
  const int bandsz = nbn << 2;
  const int band = l / bandsz;
  const int rem = l - band * bandsz;
  const int nt = rem >> 2;
  const int mt = (band << 2) + (rem & 3);
  if (ROUTE) { if (mt >= *ntiles) return; }
  const int m0 = ROUTE ? tile_s0[mt] : (mt << 8);
  const u16* Bb = B + (ROUTE ? (size_t)tile_e[mt] * (size_t)estride : 0);
  const int n0 = nt << 8;

  __shared__ u16 lds[65536];

  const int t = threadIdx.x;
  const int w = t >> 6, lane = t & 63;
  const int wst = w << 9;
  const int rt2 = t >> 2;
  const int coff = (((t & 3) ^ ((rt2 >> 1) & 3)) << 3);
  const u16* aS[2]; const u16* bS[2];
#pragma unroll
  for (int j = 0; j < 2; ++j) {
    int r = (j << 7) + rt2;
    aS[j] = A + (size_t)(m0 + r) * K + coff;
    bS[j] = Bb + (size_t)(n0 + r) * K + coff;
  }

  const int wm = w >> 2, wn = w & 3;
  const int fr = lane & 15, kq = lane >> 4;
  const int swz = ((kq ^ ((fr >> 1) & 3)) << 3);

  f32x4_t acc[8][4];
  f32x4_t zero4 = {0.f, 0.f, 0.f, 0.f};
#pragma unroll
  for (int m = 0; m < 8; ++m)
#pragma unroll
    for (int n = 0; n < 4; ++n) acc[m][n] = zero4;

  const int KT = K >> 6;
  GEMM_PROLOGUE(KT)
  GEMM_KLOOP(KT)

#pragma unroll
  for (int mf = 0; mf < 8; ++mf) {
    const int rb = (wm << 7) + (mf << 4) + (kq << 2);
#pragma unroll
    for (int rr = 0; rr < 4; ++rr) {
      const int row = m0 + rb + rr;
      if (COMBINE) {
        float* orow = (float*)Out + (size_t)row * ldo;
        int s0 = slot_of[2 * row], s1 = slot_of[2 * row + 1];
        float w0 = tok_w[2 * row], w1 = tok_w[2 * row + 1];
        const u16* pr0 = p_rt + (size_t)s0 * C_DIM;
        const u16* pr1 = p_rt + (size_t)s1 * C_DIM;
#pragma unroll
        for (int n = 0; n < 4; ++n) {
          int col = n0 + (wn << 6) + (n << 4) + fr;
          orow[col] = acc[mf][n][rr] + w0 * bf2f(pr0[col]) + w1 * bf2f(pr1[col]);
        }
      } else {
        u16* orow = (u16*)Out + (size_t)row * ldo;
#pragma unroll
        for (int n = 0; n < 4; ++n) {
          int col = n0 + (wn << 6) + (n << 4) + fr;
          orow[col] = f2bf(acc[mf][n][rr]);
        }
      }
    }
  }
}

// ---------------- host launch ----------------
extern "C" void kernel_launch(void* const* d_in, const int* in_sizes, int n_in,
                              void* d_out, int out_size, void* d_ws, size_t ws_size,
                              hipStream_t stream) {
  const float* x   = (const float*)d_in[0];
  const float* gw  = (const float*)d_in[1];
  const float* gb  = (const float*)d_in[2];
  const float* sgw = (const float*)d_in[3];
  const float* sdw = (const float*)d_in[4];
  const float* upw = (const float*)d_in[5];
  const float* dww = (const float*)d_in[6];
  float* out = (float*)d_out;

  char* ws = (char*)d_ws;
  size_t off = 0;
  auto take = [&](size_t bytes) -> void* {
    size_t o = (off + 255) & ~(size_t)255;
    off = o + bytes;
    return (void*)(ws + o);
  };

  u16* x_bf   = (u16*)take((size_t)N_TOK * C_DIM * 2);
  u16* sgw_bf = (u16*)take((size_t)(2 * HS_DIM) * C_DIM * 2);
  u16* sdw_bf = (u16*)take((size_t)C_DIM * HS_DIM * 2);
  u16* upw_bf = (u16*)take((size_t)E_NUM * (2 * H_DIM) * C_DIM * 2);   // 92.3 MB
  u16* dww_bf = (u16*)take((size_t)E_NUM * C_DIM * H_DIM * 2);
  u16* h_sh   = (u16*)take((size_t)N_TOK * HS_DIM * 2);
  u16* h_rt   = (u16*)take((size_t)NRPAD * H_DIM * 2);                 // own buffer
  u16* p_rt   = upw_bf;  // alias: upw_bf dead after routed-up GEMM (75.5 <= 92.3 MB)

  int*   tok_e    = (int*)take((size_t)N_TOK * 2 * 4);
  float* tok_w    = (float*)take((size_t)N_TOK * 2 * 4);
  int*   slot_of  = (int*)take((size_t)N_TOK * 2 * 4);
  int*   slot_tok = (int*)take((size_t)NRPAD * 4);      // zeroed span start
  int*   counts   = (int*)take(E_NUM * 4);
  int*   cursor   = (int*)take(E_NUM * 4);
  int*   ntiles   = (int*)take(4);
  int*   tile_e   = (int*)take(MAXT256 * 4);
  int*   tile_s0  = (int*)take(MAXT256 * 4);
  (void)ws_size; (void)in_sizes; (void)n_in; (void)out_size;

  // zero slot_tok + counts + cursor (contiguous span)
  size_t z0 = (size_t)((char*)slot_tok - ws);
  size_t z1 = (size_t)((char*)cursor - ws) + E_NUM * 4;
  hipMemsetAsync(ws + z0, 0, z1 - z0, stream);

  // prep: sgw+upw conversion + gate/top-2/x_bf in one heterogeneous launch
  prep_kernel<<<NBCVT + N_TOK, 256, 0, stream>>>(
      sgw, sgw_bf, 2 * HS_DIM * C_DIM / 4,
      upw, upw_bf, E_NUM * 2 * H_DIM * C_DIM / 4,
      x, gw, gb, x_bf, tok_e, tok_w, counts);

  // route: scan + tile table + slot build (single launch)
  route_kernel<<<32, 256, 0, stream>>>(
      counts, tok_e, cursor, slot_tok, slot_of, tile_e, tile_s0, ntiles);

  // merged up-GEMMs (shared + routed, fused SwiGLU) + deferred sdw/dww cvt tail
  gemm_up2<<<NBXA + NBXB + NBCV2, 512, 0, stream>>>(
      x_bf, sgw_bf, upw_bf, h_sh, h_rt, tile_e, tile_s0, ntiles, slot_tok,
      sdw, sdw_bf, dww, dww_bf);

  // routed down: p_rt[slot] = h_rt[slot] @ dww[e]^T (bf16)
  gemm256<true, false><<<MAXT256 * 8, 512, 0, stream>>>(
      h_rt, dww_bf, p_rt, C_DIM, H_DIM, 8,
      tile_e, tile_s0, ntiles, (long)C_DIM * H_DIM,
      nullptr, nullptr, nullptr);

  // shared down + combine: out = h_sh @ sdw^T + w0*p_rt[s0] + w1*p_rt[s1]
  gemm256<false, true><<<32 * 8, 512, 0, stream>>>(
      h_sh, sdw_bf, out, C_DIM, HS_DIM, 8,
      nullptr, nullptr, nullptr, 0,
      slot_of, tok_w, p_rt);
}

// Round 17
// 926.169 us; speedup vs baseline: 1.0091x; 1.0091x over previous
//
#include <hip/hip_runtime.h>
#include <hip/hip_bf16.h>
#include <stdint.h>

// Problem constants (from setup_inputs)
#define N_TOK 8192
#define C_DIM 2048
#define E_NUM 8
#define H_DIM 1408
#define HS_DIM 2816
#define NRPAD 18432      // 16384 routed slots + per-expert padding to 256
#define MAXT256 72       // 64 full tiles + 8 partial
#define NBXA 704         // shared-up blocks (32 mt x 22 nt)
#define NBXB 792         // routed-up blocks (72 mt x 11 nt)
#define NBCVT 4096       // cvt sub-grid in prep kernel

typedef unsigned short u16;
typedef float f32x4_t __attribute__((ext_vector_type(4)));
typedef short bf16x8_t __attribute__((ext_vector_type(8)));

__device__ __forceinline__ u16 f2bf(float f) {
  union { float f; uint32_t u; } c; c.f = f;
  uint32_t u = c.u;
  return (u16)((u + 0x7fffu + ((u >> 16) & 1u)) >> 16);
}
__device__ __forceinline__ float bf2f(u16 b) {
  union { uint32_t u; float f; } c; c.u = ((uint32_t)b) << 16;
  return c.f;
}

__device__ __forceinline__ void async_copy16(const u16* gsrc, u16* ldst) {
  __builtin_amdgcn_global_load_lds(
      (const __attribute__((address_space(1))) void*)gsrc,
      (__attribute__((address_space(3))) void*)ldst, 16, 0, 0);
}

#define BARRIER() asm volatile("s_barrier" ::: "memory")
#define WAITV4()  asm volatile("s_waitcnt vmcnt(4)" ::: "memory")
#define WAITV0()  asm volatile("s_waitcnt vmcnt(0)" ::: "memory")

// ---------------- prep: fused {weight cvt} + {gate/top-2/x_bf} ----------------
// Blocks [0,NBCVT): grid-stride bf16 conversion of the 4 weight tensors.
// Blocks [NBCVT, NBCVT+N_TOK): per-token gate scores, top-2, renorm, x->bf16.
__global__ __launch_bounds__(256) void prep_kernel(
    const float* __restrict__ s0, u16* __restrict__ d0, int n0,
    const float* __restrict__ s1, u16* __restrict__ d1, int n1,
    const float* __restrict__ s2, u16* __restrict__ d2, int n2,
    const float* __restrict__ s3, u16* __restrict__ d3, int n3,
    const float* __restrict__ x, const float* __restrict__ gw,
    const float* __restrict__ gbias, u16* __restrict__ x_bf,
    int* __restrict__ tok_e, float* __restrict__ tok_w, int* __restrict__ counts) {
  if (blockIdx.x < NBCVT) {
    int total = n0 + n1 + n2 + n3;
    int i = blockIdx.x * blockDim.x + threadIdx.x;
    const int stride = NBCVT * 256;
    for (; i < total; i += stride) {
      const float* src; u16* dst; int j = i;
      if (j < n0) { src = s0; dst = d0; }
      else if ((j -= n0) < n1) { src = s1; dst = d1; }
      else if ((j -= n1) < n2) { src = s2; dst = d2; }
      else { j -= n2; src = s3; dst = d3; }
      float4 v = ((const float4*)src)[j];
      ushort4 u;
      u.x = f2bf(v.x); u.y = f2bf(v.y); u.z = f2bf(v.z); u.w = f2bf(v.w);
      ((ushort4*)dst)[j] = u;
    }
    return;
  }
  int n = blockIdx.x - NBCVT;
  const float* xr = x + (size_t)n * C_DIM;
  u16* xbr = x_bf + (size_t)n * C_DIM;
  int t = threadIdx.x;
  float acc[E_NUM];
#pragma unroll
  for (int e = 0; e < E_NUM; ++e) acc[e] = 0.f;
  for (int k0 = t * 4; k0 < C_DIM; k0 += 1024) {
    float4 xv = *(const float4*)(xr + k0);
    ushort4 xb;
    xb.x = f2bf(xv.x); xb.y = f2bf(xv.y); xb.z = f2bf(xv.z); xb.w = f2bf(xv.w);
    *(ushort4*)(xbr + k0) = xb;
#pragma unroll
    for (int e = 0; e < E_NUM; ++e) {
      float4 gv = *(const float4*)(gw + e * C_DIM + k0);
      acc[e] += xv.x * gv.x + xv.y * gv.y + xv.z * gv.z + xv.w * gv.w;
    }
  }
#pragma unroll
  for (int e = 0; e < E_NUM; ++e)
    for (int off = 32; off > 0; off >>= 1) acc[e] += __shfl_xor(acc[e], off, 64);
  __shared__ float sred[4][E_NUM];
  int wid = t >> 6, lane = t & 63;
  if (lane == 0) {
#pragma unroll
    for (int e = 0; e < E_NUM; ++e) sred[wid][e] = acc[e];
  }
  __syncthreads();
  if (t == 0) {
    float sc[E_NUM];
#pragma unroll
    for (int e = 0; e < E_NUM; ++e) {
      float s = sred[0][e] + sred[1][e] + sred[2][e] + sred[3][e];
      sc[e] = 1.f / (1.f + expf(-s));
    }
    int e0 = 0; float k0v = sc[0] + gbias[0];
    for (int e = 1; e < E_NUM; ++e) {
      float ke = sc[e] + gbias[e];
      if (ke > k0v) { k0v = ke; e0 = e; }
    }
    int e1 = -1; float k1v = -1e30f;
    for (int e = 0; e < E_NUM; ++e) {
      if (e == e0) continue;
      float ke = sc[e] + gbias[e];
      if (ke > k1v) { k1v = ke; e1 = e; }
    }
    float w0 = sc[e0], w1 = sc[e1];
    float s = w0 + w1;
    w0 /= s; w1 /= s;
    tok_e[2 * n] = e0; tok_e[2 * n + 1] = e1;
    tok_w[2 * n] = w0; tok_w[2 * n + 1] = w1;
    atomicAdd(&counts[e0], 1);
    atomicAdd(&counts[e1], 1);
  }
}

// ---------------- routing scan: 256-padded offsets + tile table ----------------
__global__ void scan_route_kernel(const int* __restrict__ counts,
                                  int* __restrict__ off_pad,
                                  int* __restrict__ tile_e, int* __restrict__ tile_s0,
                                  int* __restrict__ ntiles) {
  if (threadIdx.x == 0 && blockIdx.x == 0) {
    int off = 0, t = 0;
    for (int e = 0; e < E_NUM; ++e) {
      off_pad[e] = off;
      int tiles = (counts[e] + 255) >> 8;
      for (int i = 0; i < tiles; ++i) { tile_e[t] = e; tile_s0[t] = off + i * 256; ++t; }
      off += tiles * 256;
    }
    *ntiles = t;
  }
}

__global__ __launch_bounds__(256) void build_slots_kernel(
    const int* __restrict__ tok_e, const int* __restrict__ off_pad,
    int* __restrict__ cursor, int* __restrict__ slot_tok, int* __restrict__ slot_of) {
  int n = blockIdx.x * blockDim.x + threadIdx.x;
  if (n >= N_TOK) return;
#pragma unroll
  for (int j = 0; j < 2; ++j) {
    int e = tok_e[2 * n + j];
    int pos = atomicAdd(&cursor[e], 1);
    int s = off_pad[e] + pos;
    slot_tok[s] = n;
    slot_of[2 * n + j] = s;
  }
}

// ======== shared GEMM-core macros (8-phase, single vmcnt(4)/K-tile) ==========
// Staging stream per tile kt: P1->(kt+1).A1, P2->(kt+1).B1, P3->(kt+2).A0(cur),
// P4->(kt+2).B0(cur). cur's ks0 regions are WAR-sealed by the P2/P3 barriers.
// FIFO induction (loads): enter 4 -> 6 -> 8 -> 10 -> 12 -> vmcnt(4) completes
// tile kt+1 entirely, leaves (kt+2).A0,B0 flying. Freshest waited load is 3
// phases old (~1050cy > HBM 900cy).
#define STG_A(BUF, KST, KS) \
  async_copy16(aS[0] + (KST) + (KS)*32, &lds[(BUF) + (KS)*8192 + wst]); \
  async_copy16(aS[1] + (KST) + (KS)*32, &lds[(BUF) + (KS)*8192 + 4096 + wst]);
#define STG_B(BUF, KST, KS) \
  async_copy16(bS[0] + (KST) + (KS)*32, &lds[(BUF) + 16384 + (KS)*8192 + wst]); \
  async_copy16(bS[1] + (KST) + (KS)*32, &lds[(BUF) + 16384 + (KS)*8192 + 4096 + wst]);
#define LDA(QM, KS) \
  _Pragma("unroll") \
  for (int m = 0; m < 4; ++m) { \
    int row = (wm << 7) + (QM)*64 + (m << 4) + fr; \
    afr[m] = *(const bf16x8_t*)&lds[cur + (KS)*8192 + (row << 5) + swz]; \
  }
#define LDB(KS) \
  _Pragma("unroll") \
  for (int n = 0; n < 4; ++n) { \
    int row = (wn << 6) + (n << 4) + fr; \
    bfr[n] = *(const bf16x8_t*)&lds[cur + 16384 + (KS)*8192 + (row << 5) + swz]; \
  }
#define MFMA16(QM) \
  __builtin_amdgcn_s_setprio(1); \
  _Pragma("unroll") \
  for (int m = 0; m < 4; ++m) \
    _Pragma("unroll") \
    for (int n = 0; n < 4; ++n) \
      acc[(QM)*4 + m][n] = __builtin_amdgcn_mfma_f32_16x16x32_bf16( \
          afr[m], bfr[n], acc[(QM)*4 + m][n], 0, 0, 0); \
  __builtin_amdgcn_s_setprio(0);

#define GEMM_PROLOGUE(KT) \
  STG_A(0, 0, 0); STG_B(0, 0, 0); STG_A(0, 0, 1); STG_B(0, 0, 1); \
  STG_A(32768, 64, 0); STG_B(32768, 64, 0); \
  WAITV4(); \
  BARRIER();

#define GEMM_KLOOP(KT) \
  for (int kt = 0; kt < (KT); ++kt) { \
    const int cur = (kt & 1) << 15; \
    const int nxtb = ((kt + 1) & 1) << 15; \
    const int kst1 = (kt + 1 < (KT) ? kt + 1 : kt) << 6; \
    const int kst2 = (kt + 2 < (KT) ? kt + 2 : (KT) - 1) << 6; \
    bf16x8_t afr[4], bfr[4]; \
    LDB(0); LDA(0, 0); STG_A(nxtb, kst1, 1); \
    BARRIER(); MFMA16(0); BARRIER(); \
    LDA(1, 0); STG_B(nxtb, kst1, 1); \
    BARRIER(); MFMA16(1); BARRIER(); \
    LDB(1); LDA(0, 1); STG_A(cur, kst2, 0); \
    BARRIER(); MFMA16(0); BARRIER(); \
    LDA(1, 1); STG_B(cur, kst2, 0); \
    BARRIER(); MFMA16(1); \
    WAITV4(); \
    BARRIER(); \
  } \
  WAITV0();

// ---------------- merged up-GEMM: shared-up + routed-up in ONE launch ---------
__global__ __launch_bounds__(512, 2) void gemm_up2(
    const u16* __restrict__ x_bf, const u16* __restrict__ sgw_bf,
    const u16* __restrict__ upw_bf, u16* __restrict__ h_sh, u16* __restrict__ h_rt,
    const int* __restrict__ tile_e, const int* __restrict__ tile_s0,
    const int* __restrict__ ntiles, const int* __restrict__ slot_tok) {
  const int bxr = blockIdx.x;
  const bool routed = (bxr >= NBXA);
  const int lidx = routed ? (bxr - NBXA) : bxr;
  const int nbx  = routed ? NBXB : NBXA;
  const int nbn  = routed ? 11 : 22;
  const int ldo  = routed ? H_DIM : HS_DIM;
  const int silb = routed ? 0 : HS_DIM;
  const int mulb = routed ? H_DIM : 0;
  u16* Outp      = routed ? h_rt : h_sh;

  const int chunk = nbx >> 3;
  const int l = (lidx & 7) * chunk + (lidx >> 3);
  const int bandsz = nbn << 2;
  const int band = l / bandsz;
  const int rem = l - band * bandsz;
  const int nt = rem >> 2;
  const int mt = (band << 2) + (rem & 3);
  int m0;
  const u16* Bb;
  if (routed) {
    if (mt >= *ntiles) return;
    m0 = tile_s0[mt];
    Bb = upw_bf + (size_t)tile_e[mt] * ((size_t)(2 * H_DIM) * C_DIM);
  } else {
    m0 = mt << 8;
    Bb = sgw_bf;
  }
  const int h0 = nt << 7;

  __shared__ u16 lds[65536];   // [buf(2)][mat(2)][ks(2)][256][32]

  const int t = threadIdx.x;
  const int w = t >> 6, lane = t & 63;
  const int wst = w << 9;
  const int rt2 = t >> 2;
  const int coff = (((t & 3) ^ ((rt2 >> 1) & 3)) << 3);
  const u16* aS[2]; const u16* bS[2];
#pragma unroll
  for (int j = 0; j < 2; ++j) {
    int r = (j << 7) + rt2;
    int arow = routed ? slot_tok[m0 + r] : (m0 + r);
    aS[j] = x_bf + (size_t)arow * C_DIM + coff;
    int grow = (((r >> 4) & 1) ? mulb : silb) + h0 + ((r >> 5) << 4) + (r & 15);
    bS[j] = Bb + (size_t)grow * C_DIM + coff;
  }

  const int wm = w >> 2, wn = w & 3;
  const int fr = lane & 15, kq = lane >> 4;
  const int swz = ((kq ^ ((fr >> 1) & 3)) << 3);

  f32x4_t acc[8][4];
  f32x4_t zero4 = {0.f, 0.f, 0.f, 0.f};
#pragma unroll
  for (int m = 0; m < 8; ++m)
#pragma unroll
    for (int n = 0; n < 4; ++n) acc[m][n] = zero4;

  const int KT = C_DIM >> 6;
  GEMM_PROLOGUE(KT)
  GEMM_KLOOP(KT)

  // fused SwiGLU epilogue
#pragma unroll
  for (int mf = 0; mf < 8; ++mf) {
    const int rb = (wm << 7) + (mf << 4) + (kq << 2);
#pragma unroll
    for (int rr = 0; rr < 4; ++rr) {
      const int row = m0 + rb + rr;
      u16* orow = Outp + (size_t)row * ldo;
#pragma unroll
      for (int jj = 0; jj < 2; ++jj) {
        float g = acc[mf][2 * jj][rr];
        float uu = acc[mf][2 * jj + 1][rr];
        float hv = (g / (1.f + __expf(-g))) * uu;
        orow[h0 + (wn << 5) + (jj << 4) + fr] = f2bf(hv);
      }
    }
  }
}

// ---------------- 256x256x64 8-phase bf16 GEMM (down-proj variants) ----------
template <bool ROUTE, bool COMBINE>
__global__ __launch_bounds__(512, 2) void gemm256(
    const u16* __restrict__ A, const u16* __restrict__ B,
    void* __restrict__ Out, int ldo, int K, int nbn,
    const int* __restrict__ tile_e, const int* __restrict__ tile_s0,
    const int* __restrict__ ntiles, long estride,
    const int* __restrict__ slot_of, const float* __restrict__ tok_w,
    const u16* __restrict__ p_rt) {
  const int chunk = gridDim.x >> 3;
  const int orig = blockIdx.x;
  const int l = (orig & 7) * chunk + (orig >> 3);
  const int bandsz = nbn << 2;
  const int band = l / bandsz;
  const int rem = l - band * bandsz;
  const int nt = rem >> 2;
  const int mt = (band << 2) + (rem & 3);
  if (ROUTE) { if (mt >= *ntiles) return; }
  const int m0 = ROUTE ? tile_s0[mt] : (mt << 8);
  const u16* Bb = B + (ROUTE ? (size_t)tile_e[mt] * (size_t)estride : 0);
  const int n0 = nt << 8;

  __shared__ u16 lds[65536];

  const int t = threadIdx.x;
  const int w = t >> 6, lane = t & 63;
  const int wst = w << 9;
  const int rt2 = t >> 2;
  const int coff = (((t & 3) ^ ((rt2 >> 1) & 3)) << 3);
  const u16* aS[2]; const u16* bS[2];
#pragma unroll
  for (int j = 0; j < 2; ++j) {
    int r = (j << 7) + rt2;
    aS[j] = A + (size_t)(m0 + r) * K + coff;
    bS[j] = Bb + (size_t)(n0 + r) * K + coff;
  }

  const int wm = w >> 2, wn = w & 3;
  const int fr = lane & 15, kq = lane >> 4;
  const int swz = ((kq ^ ((fr >> 1) & 3)) << 3);

  f32x4_t acc[8][4];
  f32x4_t zero4 = {0.f, 0.f, 0.f, 0.f};
#pragma unroll
  for (int m = 0; m < 8; ++m)
#pragma unroll
    for (int n = 0; n < 4; ++n) acc[m][n] = zero4;

  const int KT = K >> 6;
  GEMM_PROLOGUE(KT)
  GEMM_KLOOP(KT)

#pragma unroll
  for (int mf = 0; mf < 8; ++mf) {
    const int rb = (wm << 7) + (mf << 4) + (kq << 2);
#pragma unroll
    for (int rr = 0; rr < 4; ++rr) {
      const int row = m0 + rb + rr;
      if (COMBINE) {
        float* orow = (float*)Out + (size_t)row * ldo;
        int s0 = slot_of[2 * row], s1 = slot_of[2 * row + 1];
        float w0 = tok_w[2 * row], w1 = tok_w[2 * row + 1];
        const u16* pr0 = p_rt + (size_t)s0 * C_DIM;
        const u16* pr1 = p_rt + (size_t)s1 * C_DIM;
#pragma unroll
        for (int n = 0; n < 4; ++n) {
          int col = n0 + (wn << 6) + (n << 4) + fr;
          orow[col] = acc[mf][n][rr] + w0 * bf2f(pr0[col]) + w1 * bf2f(pr1[col]);
        }
      } else {
        u16* orow = (u16*)Out + (size_t)row * ldo;
#pragma unroll
        for (int n = 0; n < 4; ++n) {
          int col = n0 + (wn << 6) + (n << 4) + fr;
          orow[col] = f2bf(acc[mf][n][rr]);
        }
      }
    }
  }
}

// ---------------- host launch ----------------
extern "C" void kernel_launch(void* const* d_in, const int* in_sizes, int n_in,
                              void* d_out, int out_size, void* d_ws, size_t ws_size,
                              hipStream_t stream) {
  const float* x   = (const float*)d_in[0];
  const float* gw  = (const float*)d_in[1];
  const float* gb  = (const float*)d_in[2];
  const float* sgw = (const float*)d_in[3];
  const float* sdw = (const float*)d_in[4];
  const float* upw = (const float*)d_in[5];
  const float* dww = (const float*)d_in[6];
  float* out = (float*)d_out;

  char* ws = (char*)d_ws;
  size_t off = 0;
  auto take = [&](size_t bytes) -> void* {
    size_t o = (off + 255) & ~(size_t)255;
    off = o + bytes;
    return (void*)(ws + o);
  };

  u16* x_bf   = (u16*)take((size_t)N_TOK * C_DIM * 2);
  u16* sgw_bf = (u16*)take((size_t)(2 * HS_DIM) * C_DIM * 2);
  u16* sdw_bf = (u16*)take((size_t)C_DIM * HS_DIM * 2);
  u16* upw_bf = (u16*)take((size_t)E_NUM * (2 * H_DIM) * C_DIM * 2);   // 92.3 MB
  u16* dww_bf = (u16*)take((size_t)E_NUM * C_DIM * H_DIM * 2);
  u16* h_sh   = (u16*)take((size_t)N_TOK * HS_DIM * 2);
  u16* h_rt   = (u16*)take((size_t)NRPAD * H_DIM * 2);                 // own buffer
  u16* p_rt   = upw_bf;  // alias: upw_bf dead after routed-up GEMM (75.5 <= 92.3 MB)

  int*   tok_e    = (int*)take((size_t)N_TOK * 2 * 4);
  float* tok_w    = (float*)take((size_t)N_TOK * 2 * 4);
  int*   slot_of  = (int*)take((size_t)N_TOK * 2 * 4);
  int*   slot_tok = (int*)take((size_t)NRPAD * 4);      // zeroed span start
  int*   counts   = (int*)take(E_NUM * 4);
  int*   cursor   = (int*)take(E_NUM * 4);
  int*   off_pad  = (int*)take(E_NUM * 4);
  int*   ntiles   = (int*)take(4);
  int*   tile_e   = (int*)take(MAXT256 * 4);
  int*   tile_s0  = (int*)take(MAXT256 * 4);
  (void)ws_size; (void)in_sizes; (void)n_in; (void)out_size;

  // zero slot_tok + counts + cursor (contiguous span)
  size_t z0 = (size_t)((char*)slot_tok - ws);
  size_t z1 = (size_t)((char*)cursor - ws) + E_NUM * 4;
  hipMemsetAsync(ws + z0, 0, z1 - z0, stream);

  // prep: weight conversion + gate/top-2/x_bf in one heterogeneous launch
  prep_kernel<<<NBCVT + N_TOK, 256, 0, stream>>>(
      sgw, sgw_bf, 2 * HS_DIM * C_DIM / 4,
      sdw, sdw_bf, C_DIM * HS_DIM / 4,
      upw, upw_bf, E_NUM * 2 * H_DIM * C_DIM / 4,
      dww, dww_bf, E_NUM * C_DIM * H_DIM / 4,
      x, gw, gb, x_bf, tok_e, tok_w, counts);

  scan_route_kernel<<<1, 64, 0, stream>>>(counts, off_pad, tile_e, tile_s0, ntiles);
  build_slots_kernel<<<32, 256, 0, stream>>>(tok_e, off_pad, cursor, slot_tok, slot_of);

  // merged up-GEMMs (shared + routed, fused SwiGLU) in ONE launch
  gemm_up2<<<NBXA + NBXB, 512, 0, stream>>>(
      x_bf, sgw_bf, upw_bf, h_sh, h_rt, tile_e, tile_s0, ntiles, slot_tok);

  // routed down: p_rt[slot] = h_rt[slot] @ dww[e]^T (bf16)
  gemm256<true, false><<<MAXT256 * 8, 512, 0, stream>>>(
      h_rt, dww_bf, p_rt, C_DIM, H_DIM, 8,
      tile_e, tile_s0, ntiles, (long)C_DIM * H_DIM,
      nullptr, nullptr, nullptr);

  // shared down + combine: out = h_sh @ sdw^T + w0*p_rt[s0] + w1*p_rt[s1]
  gemm256<false, true><<<32 * 8, 512, 0, stream>>>(
      h_sh, sdw_bf, out, C_DIM, HS_DIM, 8,
      nullptr, nullptr, nullptr, 0,
      slot_of, tok_w, p_rt);
}